// Round 3
// baseline (137.773 us; speedup 1.0000x reference)
//
#include <hip/hip_runtime.h>

// myAttention: B=1M batches, D=16, T=4.
// Per batch: x=[16,4] (cols = the 4 inputs), M = x^T x (4x4),
// att = softmax over rows (axis=1, per-column normalization),
// output[d] = sum_i x[d][i] * w[i],  w[i] = sum_j att[i][j].
// Memory-bound: 402 MB logical traffic -> ~64 us floor @ 6.3 TB/s.
//
// Round 1 post-mortem: VGPR=48 (< the 64 needed for x alone) forced the
// compiler to serialize loads -> latency-bound (VALUBusy 7%, HBM 14%).
// Fix: __launch_bounds__(256,4) -> 128 VGPR budget, all 16 loads in flight.
// Round 2 fix: __builtin_nontemporal_store needs a clang ext_vector type,
// not HIP's float4 class.

typedef float v4f __attribute__((ext_vector_type(4)));

__global__ __launch_bounds__(256, 4) void myattn_kernel(
    const float* __restrict__ in0, const float* __restrict__ in1,
    const float* __restrict__ in2, const float* __restrict__ in3,
    float* __restrict__ out, float* __restrict__ att_out, int B)
{
    int b = blockIdx.x * blockDim.x + threadIdx.x;
    if (b >= B) return;
    size_t base = (size_t)b * 16;

    // Issue ALL 16 16B loads up front; keep full x resident (64 VGPRs).
    v4f xv[4][4];
    {
        const v4f* p0 = reinterpret_cast<const v4f*>(in0 + base);
        const v4f* p1 = reinterpret_cast<const v4f*>(in1 + base);
        const v4f* p2 = reinterpret_cast<const v4f*>(in2 + base);
        const v4f* p3 = reinterpret_cast<const v4f*>(in3 + base);
        #pragma unroll
        for (int v = 0; v < 4; ++v) xv[0][v] = p0[v];
        #pragma unroll
        for (int v = 0; v < 4; ++v) xv[1][v] = p1[v];
        #pragma unroll
        for (int v = 0; v < 4; ++v) xv[2][v] = p2[v];
        #pragma unroll
        for (int v = 0; v < 4; ++v) xv[3][v] = p3[v];
    }
    // Flat view x[q][d]
    float x[4][16];
    #pragma unroll
    for (int q = 0; q < 4; ++q) {
        #pragma unroll
        for (int v = 0; v < 4; ++v) {
            #pragma unroll
            for (int e = 0; e < 4; ++e)
                x[q][v*4+e] = xv[q][v][e];
        }
    }

    // M[i][j] = sum_d x[i][d] * x[j][d]  (symmetric, 10 unique dots)
    float M[4][4];
    #pragma unroll
    for (int i = 0; i < 4; ++i) {
        #pragma unroll
        for (int j = i; j < 4; ++j) {
            float s = 0.f;
            #pragma unroll
            for (int d = 0; d < 16; ++d) s = fmaf(x[i][d], x[j][d], s);
            M[i][j] = s;
            M[j][i] = s;
        }
    }

    // softmax over axis=1 (rows i), per column j
    float att[4][4];
    #pragma unroll
    for (int j = 0; j < 4; ++j) {
        float m = fmaxf(fmaxf(M[0][j], M[1][j]), fmaxf(M[2][j], M[3][j]));
        float e0 = __expf(M[0][j] - m);
        float e1 = __expf(M[1][j] - m);
        float e2 = __expf(M[2][j] - m);
        float e3 = __expf(M[3][j] - m);
        float inv = 1.f / (e0 + e1 + e2 + e3);
        att[0][j] = e0 * inv;
        att[1][j] = e1 * inv;
        att[2][j] = e2 * inv;
        att[3][j] = e3 * inv;
    }

    // w[i] = sum_j att[i][j];  output[d] = sum_i x[i][d] * w[i]
    float w[4];
    #pragma unroll
    for (int i = 0; i < 4; ++i)
        w[i] = att[i][0] + att[i][1] + att[i][2] + att[i][3];

    v4f* po = reinterpret_cast<v4f*>(out + base);
    #pragma unroll
    for (int v = 0; v < 4; ++v) {
        v4f t;
        #pragma unroll
        for (int e = 0; e < 4; ++e)
            t[e] = fmaf(x[0][v*4+e], w[0], fmaf(x[1][v*4+e], w[1],
                   fmaf(x[2][v*4+e], w[2], x[3][v*4+e] * w[3])));
        __builtin_nontemporal_store(t, po + v);
    }

    // att output: [B, i, j] row-major -> one 16B store per row i
    v4f* pa = reinterpret_cast<v4f*>(att_out + base);
    #pragma unroll
    for (int i = 0; i < 4; ++i) {
        v4f a = { att[i][0], att[i][1], att[i][2], att[i][3] };
        __builtin_nontemporal_store(a, pa + i);
    }
}

extern "C" void kernel_launch(void* const* d_in, const int* in_sizes, int n_in,
                              void* d_out, int out_size, void* d_ws, size_t ws_size,
                              hipStream_t stream) {
    int B = in_sizes[0] / 16;
    const float* in0 = (const float*)d_in[0];
    const float* in1 = (const float*)d_in[1];
    const float* in2 = (const float*)d_in[2];
    const float* in3 = (const float*)d_in[3];
    float* out = (float*)d_out;
    float* att = out + (size_t)B * 16;

    const int threads = 256;
    const int blocks = (B + threads - 1) / threads;
    myattn_kernel<<<blocks, threads, 0, stream>>>(in0, in1, in2, in3, out, att, B);
}

// Round 4
// 77.258 us; speedup vs baseline: 1.7833x; 1.7833x over previous
//
#include <hip/hip_runtime.h>

// myAttention: B=1M batches, D=16, T=4.
// x=[16,4] per batch (cols = inputs), M = x^T x (4x4),
// att = softmax over rows (axis=1, per-column norm),
// out[d] = sum_i x[d][i]*w[i], w[i] = sum_j att[i][j].
//
// Round 3 post-mortem: one-batch-per-thread made every vector mem
// instruction touch 64 distinct cache lines (lane stride 64B) ->
// address-coalescing bound at ~14% HBM BW. NT stores regressed (bypass L3).
//
// Round 4: QUAD-PER-BATCH. 4 threads share a batch; thread e owns
// features 4e..4e+3 of all 4 inputs. All loads/stores are float4 at
// byte offset tid*16 -> perfectly contiguous across the wave (1 KiB/instr).
// M is quad-reduced via __shfl_xor 1,2 (DPP quad-perm, stays in quad).
// Softmax recomputed per-thread (redundant x4, ~16 exp - cheap vs mem floor).

typedef float v4f __attribute__((ext_vector_type(4)));

__global__ __launch_bounds__(256) void myattn_kernel(
    const float* __restrict__ in0, const float* __restrict__ in1,
    const float* __restrict__ in2, const float* __restrict__ in3,
    float* __restrict__ out, float* __restrict__ att_out, int B)
{
    int t = blockIdx.x * blockDim.x + threadIdx.x;   // [0, 4*B)
    int b = t >> 2;                                   // batch
    if (b >= B) return;
    size_t fbase = (size_t)t * 4;                     // float offset = b*16 + e*4

    // Each thread: one float4 per input (features 4e..4e+3). Coalesced.
    v4f xq[4];
    xq[0] = *reinterpret_cast<const v4f*>(in0 + fbase);
    xq[1] = *reinterpret_cast<const v4f*>(in1 + fbase);
    xq[2] = *reinterpret_cast<const v4f*>(in2 + fbase);
    xq[3] = *reinterpret_cast<const v4f*>(in3 + fbase);

    // Partial M over this thread's 4 features, then quad butterfly-reduce.
    float M[4][4];
    #pragma unroll
    for (int i = 0; i < 4; ++i) {
        #pragma unroll
        for (int j = i; j < 4; ++j) {
            float s = xq[i][0] * xq[j][0];
            s = fmaf(xq[i][1], xq[j][1], s);
            s = fmaf(xq[i][2], xq[j][2], s);
            s = fmaf(xq[i][3], xq[j][3], s);
            s += __shfl_xor(s, 1);   // within-quad reduce (DPP)
            s += __shfl_xor(s, 2);
            M[i][j] = s;
            M[j][i] = s;
        }
    }

    // softmax over axis=1 (rows i), per column j — full, redundant per thread
    float att[4][4];
    #pragma unroll
    for (int j = 0; j < 4; ++j) {
        float m = fmaxf(fmaxf(M[0][j], M[1][j]), fmaxf(M[2][j], M[3][j]));
        float e0 = __expf(M[0][j] - m);
        float e1 = __expf(M[1][j] - m);
        float e2 = __expf(M[2][j] - m);
        float e3 = __expf(M[3][j] - m);
        float inv = 1.f / (e0 + e1 + e2 + e3);
        att[0][j] = e0 * inv;
        att[1][j] = e1 * inv;
        att[2][j] = e2 * inv;
        att[3][j] = e3 * inv;
    }

    // w[i] = sum_j att[i][j]; out slice: out[4e+k] = sum_i x[i][4e+k]*w[i]
    float w[4];
    #pragma unroll
    for (int i = 0; i < 4; ++i)
        w[i] = att[i][0] + att[i][1] + att[i][2] + att[i][3];

    v4f o;
    #pragma unroll
    for (int k = 0; k < 4; ++k)
        o[k] = fmaf(xq[0][k], w[0], fmaf(xq[1][k], w[1],
               fmaf(xq[2][k], w[2], xq[3][k] * w[3])));
    *reinterpret_cast<v4f*>(out + fbase) = o;

    // att output [B,4,4] row-major: thread e stores row i=e ->
    // float offset b*16 + e*4 == fbase. Coalesced.
    int e = t & 3;
    v4f a = { att[e][0], att[e][1], att[e][2], att[e][3] };
    *reinterpret_cast<v4f*>(att_out + fbase) = a;
}

extern "C" void kernel_launch(void* const* d_in, const int* in_sizes, int n_in,
                              void* d_out, int out_size, void* d_ws, size_t ws_size,
                              hipStream_t stream) {
    int B = in_sizes[0] / 16;
    const float* in0 = (const float*)d_in[0];
    const float* in1 = (const float*)d_in[1];
    const float* in2 = (const float*)d_in[2];
    const float* in3 = (const float*)d_in[3];
    float* out = (float*)d_out;
    float* att = out + (size_t)B * 16;

    const int threads = 256;
    const long long total = 4LL * B;
    const int blocks = (int)((total + threads - 1) / threads);
    myattn_kernel<<<blocks, threads, 0, stream>>>(in0, in1, in2, in3, out, att, B);
}

// Round 5
// 62.132 us; speedup vs baseline: 2.2174x; 1.2435x over previous
//
#include <hip/hip_runtime.h>

// myAttention: B=1M batches, D=16, T=4.
// x=[16,4] per batch (cols = inputs), M = x^T x (4x4),
// att = softmax over rows (axis=1, per-column norm),
// out[d] = sum_i x[d][i]*w[i], w[i] = sum_j att[i][j].
//
// R4 (quad-per-batch, coalesced float4): 77 us, 5.2 TB/s logical (83% of copy
// ceiling). FETCH=134MB of 268MB logical -> inputs half L3-resident; the
// 128 MiB output write stream evicts them.
// R5: nontemporal stores (outputs are write-once, never read) so writes don't
// allocate in L3 -> inputs stay resident, fetch drops, write-bound floor ~21us.
// (R3's NT regression was confounded by uncoalesced 16B/lane stores ->
// partial-line HBM writes. Now stores are dense 1KiB/wave segments.)

typedef float v4f __attribute__((ext_vector_type(4)));

__global__ __launch_bounds__(256) void myattn_kernel(
    const float* __restrict__ in0, const float* __restrict__ in1,
    const float* __restrict__ in2, const float* __restrict__ in3,
    float* __restrict__ out, float* __restrict__ att_out, int B)
{
    int t = blockIdx.x * blockDim.x + threadIdx.x;   // [0, 4*B)
    int b = t >> 2;                                   // batch
    if (b >= B) return;
    size_t fbase = (size_t)t * 4;                     // float offset = b*16 + e*4

    // Each thread: one float4 per input (features 4e..4e+3). Coalesced.
    v4f xq[4];
    xq[0] = *reinterpret_cast<const v4f*>(in0 + fbase);
    xq[1] = *reinterpret_cast<const v4f*>(in1 + fbase);
    xq[2] = *reinterpret_cast<const v4f*>(in2 + fbase);
    xq[3] = *reinterpret_cast<const v4f*>(in3 + fbase);

    // Partial M over this thread's 4 features, then quad butterfly-reduce.
    float M[4][4];
    #pragma unroll
    for (int i = 0; i < 4; ++i) {
        #pragma unroll
        for (int j = i; j < 4; ++j) {
            float s = xq[i][0] * xq[j][0];
            s = fmaf(xq[i][1], xq[j][1], s);
            s = fmaf(xq[i][2], xq[j][2], s);
            s = fmaf(xq[i][3], xq[j][3], s);
            s += __shfl_xor(s, 1);   // within-quad reduce (DPP)
            s += __shfl_xor(s, 2);
            M[i][j] = s;
            M[j][i] = s;
        }
    }

    // softmax over axis=1 (rows i), per column j — full, redundant per thread
    float att[4][4];
    #pragma unroll
    for (int j = 0; j < 4; ++j) {
        float m = fmaxf(fmaxf(M[0][j], M[1][j]), fmaxf(M[2][j], M[3][j]));
        float e0 = __expf(M[0][j] - m);
        float e1 = __expf(M[1][j] - m);
        float e2 = __expf(M[2][j] - m);
        float e3 = __expf(M[3][j] - m);
        float inv = 1.f / (e0 + e1 + e2 + e3);
        att[0][j] = e0 * inv;
        att[1][j] = e1 * inv;
        att[2][j] = e2 * inv;
        att[3][j] = e3 * inv;
    }

    // w[i] = sum_j att[i][j]; out slice: out[4e+k] = sum_i x[i][4e+k]*w[i]
    float w[4];
    #pragma unroll
    for (int i = 0; i < 4; ++i)
        w[i] = att[i][0] + att[i][1] + att[i][2] + att[i][3];

    v4f o;
    #pragma unroll
    for (int k = 0; k < 4; ++k)
        o[k] = fmaf(xq[0][k], w[0], fmaf(xq[1][k], w[1],
               fmaf(xq[2][k], w[2], xq[3][k] * w[3])));
    __builtin_nontemporal_store(o, reinterpret_cast<v4f*>(out + fbase));

    // att output [B,4,4] row-major: thread e stores row i=e ->
    // float offset b*16 + e*4 == fbase. Coalesced.
    int e = t & 3;
    v4f a = { att[e][0], att[e][1], att[e][2], att[e][3] };
    __builtin_nontemporal_store(a, reinterpret_cast<v4f*>(att_out + fbase));
}

extern "C" void kernel_launch(void* const* d_in, const int* in_sizes, int n_in,
                              void* d_out, int out_size, void* d_ws, size_t ws_size,
                              hipStream_t stream) {
    int B = in_sizes[0] / 16;
    const float* in0 = (const float*)d_in[0];
    const float* in1 = (const float*)d_in[1];
    const float* in2 = (const float*)d_in[2];
    const float* in3 = (const float*)d_in[3];
    float* out = (float*)d_out;
    float* att = out + (size_t)B * 16;

    const int threads = 256;
    const long long total = 4LL * B;
    const int blocks = (int)((total + threads - 1) / threads);
    myattn_kernel<<<blocks, threads, 0, stream>>>(in0, in1, in2, in3, out, att, B);
}